// Round 14
// baseline (61.081 us; speedup 1.0000x reference)
//
#include <hip/hip_runtime.h>

// Problem constants (fixed by setup_inputs)
#define NB 16          // graphs
#define NN 256         // nodes per graph
#define ND 64          // emb dim
#define EPG 4096       // edges per graph
#define NE (NB*EPG)    // 65536 edges
#define NNODE (NB*NN)  // 4096 global rows
#define MAXE_ROW 256   // max possible edges per row

typedef float f4 __attribute__((ext_vector_type(4)));
typedef int   i4 __attribute__((ext_vector_type(4)));

// rocclr-fillBuffer clone (R12/R13 winner): 65536 threads, branch-free
// unconditional f4 stores, no LDS, no loads in the loop. Patched after.
__global__ __launch_bounds__(256) void fill_kernel(const float* __restrict__ emb,
                                                   f4* __restrict__ out) {
    constexpr int nth    = 256 * 256;                // 65536 threads
    constexpr int total4 = NB * NN * NN * (ND / 4);  // 16,777,216 f4
    const int tid = blockIdx.x * 256 + threadIdx.x;
    const f4 v2 = ((const f4*)(emb + 2 * ND))[threadIdx.x & 15];  // background
    #pragma unroll 16
    for (int i = 0; i < total4 / nth; ++i)           // 256 iters, pure store stream
        out[tid + i * nth] = v2;
}

// Row-ordered patch: one block per output row. Scan graph's src list (L2-hot,
// shared by the graph's 256 blocks) -> LDS edge list; write diag cell + edge
// cells. All writes confined to this row's 64 KB span; blocks in ascending
// row order -> DRAM-page-friendly write stream instead of random scatter.
__global__ __launch_bounds__(256) void row_patch(const float* __restrict__ edge_attr,
                                                 const int* __restrict__ edge_index,
                                                 const float* __restrict__ emb,
                                                 f4* __restrict__ out) {
    __shared__ int lcnt;
    __shared__ int llist[MAXE_ROW];    // (e << 8) | ld
    const int row = blockIdx.x;        // global row 0..4095
    const int g   = row >> 8;          // graph
    const int tid = threadIdx.x;

    if (tid == 0) lcnt = 0;
    __syncthreads();

    // scan this graph's src array (4096 ints = 1024 int4; L2-resident)
    const i4* __restrict__ srcv = (const i4*)(edge_index + g * EPG);
    #pragma unroll
    for (int k = 0; k < 4; ++k) {
        const int vi = tid + k * 256;
        const i4 s = srcv[vi];
        #pragma unroll
        for (int j = 0; j < 4; ++j) {
            if (s[j] == row) {
                const int e  = g * EPG + vi * 4 + j;
                const int ld = edge_index[NE + e] & (NN - 1);
                const int p  = atomicAdd(&lcnt, 1);
                llist[p] = (e << 8) | ld;
            }
        }
    }
    __syncthreads();

    const int dq = tid & 15;           // f4 slot within a cell
    f4* __restrict__ rowout = out + (long)row * NN * (ND / 4);

    // diagonal cell of this row (16 lanes, one 256 B cell)
    if (tid < 16)
        rowout[(row & (NN - 1)) * (ND / 4) + tid] = ((const f4*)(emb + 1 * ND))[tid];

    // edge cells (mean 16/row; 16 lanes per edge; reads coalesced, writes
    // within this row's 64 KB span)
    const int cnt = lcnt;
    for (int k = tid >> 4; k < cnt; k += 16) {
        const int pk = llist[k];
        const int e  = pk >> 8;
        const int ld = pk & 255;
        rowout[ld * (ND / 4) + dq] =
            __builtin_nontemporal_load((const f4*)edge_attr + (long)e * (ND / 4) + dq);
    }
}

extern "C" void kernel_launch(void* const* d_in, const int* in_sizes, int n_in,
                              void* d_out, int out_size, void* d_ws, size_t ws_size,
                              hipStream_t stream) {
    const float* edge_attr  = (const float*)d_in[0];
    const float* emb_table  = (const float*)d_in[1];
    const int*   edge_index = (const int*)d_in[2];
    // d_in[3] = batch_vec — unused (indices derivable from src/dst bit math)
    f4* out = (f4*)d_out;

    fill_kernel<<<256, 256, 0, stream>>>(emb_table, out);
    row_patch<<<NNODE, 256, 0, stream>>>(edge_attr, edge_index, emb_table, out);
}